// Round 1
// baseline (73.780 us; speedup 1.0000x reference)
//
#include <hip/hip_runtime.h>

// Geometric product in G(3,0,0), short-lex blade order:
//   [0]=1, [1]=e1, [2]=e2, [3]=e3, [4]=e12, [5]=e13, [6]=e23, [7]=e123
// Multiplication table hardcoded (Cayley tensor is a fixed ±1 sparse tensor:
// each (i,j) pair contributes to exactly one k). 64 FMAs per multivector.
// Memory-bound: 96 B/MV -> ~403 MB total -> ~64 us roofline at 6.3 TB/s.

__global__ __launch_bounds__(256) void gp3_kernel(const float4* __restrict__ a,
                                                  const float4* __restrict__ b,
                                                  float4* __restrict__ out,
                                                  int n_mv)
{
    int idx = blockIdx.x * blockDim.x + threadIdx.x;
    if (idx >= n_mv) return;

    float4 al = a[2 * idx];
    float4 ah = a[2 * idx + 1];
    float4 bl = b[2 * idx];
    float4 bh = b[2 * idx + 1];

    float a0 = al.x, a1 = al.y, a2 = al.z, a3 = al.w;
    float a4 = ah.x, a5 = ah.y, a6 = ah.z, a7 = ah.w;
    float b0 = bl.x, b1 = bl.y, b2 = bl.z, b3 = bl.w;
    float b4 = bh.x, b5 = bh.y, b6 = bh.z, b7 = bh.w;

    // scalar
    float o0 = a0*b0 + a1*b1 + a2*b2 + a3*b3 - a4*b4 - a5*b5 - a6*b6 - a7*b7;
    // e1
    float o1 = a0*b1 + a1*b0 - a2*b4 + a4*b2 - a3*b5 + a5*b3 - a6*b7 - a7*b6;
    // e2
    float o2 = a0*b2 + a2*b0 + a1*b4 - a4*b1 - a3*b6 + a6*b3 + a5*b7 + a7*b5;
    // e3
    float o3 = a0*b3 + a3*b0 + a1*b5 - a5*b1 + a2*b6 - a6*b2 - a4*b7 - a7*b4;
    // e12
    float o4 = a0*b4 + a4*b0 + a1*b2 - a2*b1 - a5*b6 + a6*b5 + a3*b7 + a7*b3;
    // e13
    float o5 = a0*b5 + a5*b0 + a1*b3 - a3*b1 + a4*b6 - a6*b4 - a2*b7 - a7*b2;
    // e23
    float o6 = a0*b6 + a6*b0 + a2*b3 - a3*b2 - a4*b5 + a5*b4 + a1*b7 + a7*b1;
    // e123
    float o7 = a0*b7 + a7*b0 + a1*b6 + a6*b1 - a2*b5 - a5*b2 + a3*b4 + a4*b3;

    out[2 * idx]     = make_float4(o0, o1, o2, o3);
    out[2 * idx + 1] = make_float4(o4, o5, o6, o7);
}

extern "C" void kernel_launch(void* const* d_in, const int* in_sizes, int n_in,
                              void* d_out, int out_size, void* d_ws, size_t ws_size,
                              hipStream_t stream) {
    const float4* a = (const float4*)d_in[0];
    const float4* b = (const float4*)d_in[1];
    // d_in[2] is the cayley tensor [8,8,8] — fixed for METRIC=[1,1,1], hardcoded above.
    float4* out = (float4*)d_out;

    int n_mv = in_sizes[0] / 8;
    int block = 256;
    int grid = (n_mv + block - 1) / block;
    gp3_kernel<<<grid, block, 0, stream>>>(a, b, out, n_mv);
}